// Round 5
// baseline (64.564 us; speedup 1.0000x reference)
//
#include <hip/hip_runtime.h>

typedef unsigned int u32;
typedef unsigned long long u64;

// ---------------------------------------------------------------------------
// Output layout (float32, 414 elems):
//  [0..3] confmat [tn,fp,fn,tp]; [4] map_; [5..105] prec_t; [106..206] rec_t;
//  [207..307] ths; [308..408] spec_t; [409..413] recall,precision,specificity,
//  accuracy, loss_out
//
// Fine histogram: 4096 bins = 102 threshold-aligned regions x 40 sub-bins.
// Region k holds elements with  (k-1)*0.01f < p1 <= k*0.01f  (float compares
// self-consistent with our p1), so threshold counts are exact prefix sums over
// whole regions. Sub-bins order elements within a region for AP ranks.
//
// Workspace layout:
//  partials: NBLK*K*4 (u32 packed count|pos<<16, per main block)
//  fineHist: K*8      (u64 packed count|pos<<32)
//  counters: 32B      (u32 [0]=tp [1]=lblSum [2]=predSum)
//  prefixD:  K*8      (u64 exclusive descending prefix; d=0 is highest bin)
//  apPartial: APB*8   (double per ap block)
// ---------------------------------------------------------------------------

#define K     4096
#define NBLK  512
#define TPB   1024
#define APB   256

static __device__ __forceinline__ float safe_div_f(float a, float b) {
    return (b > 0.0f) ? (a / fmaxf(b, 1.0f)) : 0.0f;
}

static __device__ __forceinline__ void proc(
    float l0, float l1, int lbl,
    u32& tp, u32& lblS, u32& predS, u32* __restrict__ fineLDS)
{
    float d = l1 - l0;
    u32 pred = (d > 0.0f) ? 1u : 0u;            // argmax: ties -> 0
    float e = __expf(-fabsf(d));                // in (0,1]
    float pl = e * __builtin_amdgcn_rcpf(1.0f + e);   // min(p1,1-p1), fast rcp
    float p1 = pred ? (1.0f - pl) : pl;

    tp    += ((u32)lbl & pred);
    lblS  += (u32)lbl;
    predS += pred;

    // smallest k in [0,101] with p1 <= (float)k * 0.01f (self-consistent)
    int k = (int)ceilf(p1 * 100.0f);
    k = min(max(k, 0), 101);
    if (k > 0 && p1 <= (float)(k - 1) * 0.01f) --k;
    else if (k <= 100 && p1 > (float)k * 0.01f) ++k;

    // 40 sub-bins within region k (ordering only; need not be exact)
    float lo = (float)(k - 1) * 0.01f;
    int sub = (int)((p1 - lo) * 4000.0f);
    sub = min(max(sub, 0), 39);

    atomicAdd(&fineLDS[k * 40 + sub], 1u | ((u32)lbl << 16));
}

__global__ void __launch_bounds__(TPB, 8)
main_pass(const float* __restrict__ logits, const int* __restrict__ targets,
          int N, u32* __restrict__ partials, u32* __restrict__ counters)
{
    __shared__ u32 fineLDS[K];
    __shared__ u32 sConf[3];

    const int t = threadIdx.x;
    for (int i = t; i < K; i += TPB) fineLDS[i] = 0u;
    if (t < 3) sConf[t] = 0u;
    __syncthreads();

    const int nPairs = N >> 1;                   // pair = (float4 logits, int2 tg)
    const int S = NBLK * TPB;                    // total threads
    const float4* __restrict__ lp = (const float4*)logits;
    const int2*   __restrict__ tg = (const int2*)targets;

    u32 tp = 0u, lblS = 0u, predS = 0u;

    int p = blockIdx.x * TPB + t;
    bool v0 = p < nPairs;
    bool v1 = (p + S) < nPairs;

    // prologue: load current buffer (lane-contiguous float4 / int2)
    float4 a0, a1; int2 b0, b1;
    if (v0) { a0 = lp[p];     b0 = tg[p]; }
    if (v1) { a1 = lp[p + S]; b1 = tg[p + S]; }

    // software pipeline: issue next-iteration loads BEFORE processing current
    while (v0) {
        const int pn = p + 2 * S;
        const bool w0 = pn < nPairs;
        const bool w1 = (pn + S) < nPairs;
        float4 na0, na1; int2 nb0, nb1;
        if (w0) { na0 = lp[pn];     nb0 = tg[pn]; }
        if (w1) { na1 = lp[pn + S]; nb1 = tg[pn + S]; }

        proc(a0.x, a0.y, b0.x, tp, lblS, predS, fineLDS);
        proc(a0.z, a0.w, b0.y, tp, lblS, predS, fineLDS);
        if (v1) {
            proc(a1.x, a1.y, b1.x, tp, lblS, predS, fineLDS);
            proc(a1.z, a1.w, b1.y, tp, lblS, predS, fineLDS);
        }

        a0 = na0; b0 = nb0; a1 = na1; b1 = nb1;
        v0 = w0; v1 = w1; p = pn;
    }

    // odd-N tail (N even for this problem; kept for generality)
    if (blockIdx.x == 0 && t == 0 && (N & 1)) {
        int last = N - 1;
        proc(logits[2 * last], logits[2 * last + 1], targets[last],
             tp, lblS, predS, fineLDS);
    }

    #pragma unroll
    for (int off = 32; off > 0; off >>= 1) {
        tp    += __shfl_down(tp, off);
        lblS  += __shfl_down(lblS, off);
        predS += __shfl_down(predS, off);
    }
    if ((t & 63) == 0) {
        atomicAdd(&sConf[0], tp);
        atomicAdd(&sConf[1], lblS);
        atomicAdd(&sConf[2], predS);
    }
    __syncthreads();
    if (t < 3 && sConf[t]) atomicAdd(&counters[t], sConf[t]);

    // non-atomic coalesced flush
    u32* dst = partials + (size_t)blockIdx.x * K;
    for (int i2 = t; i2 < K; i2 += TPB) dst[i2] = fineLDS[i2];
}

// Fold NBLK slices into u64 fineHist. grid = 16 chunks x 8 groups = 128 blocks.
__global__ void __launch_bounds__(256)
reduce_hist(const u32* __restrict__ partials, u64* __restrict__ fineHist)
{
    const int chunk = blockIdx.x & 15;
    const int grp   = blockIdx.x >> 4;          // 0..7, 64 slices each
    const int bin = chunk * 256 + threadIdx.x;
    u32 cnt = 0u, pos = 0u;
    const u32* p = partials + (size_t)(grp * 64) * K + bin;
    #pragma unroll 8
    for (int s = 0; s < 64; ++s) {
        u32 v = p[(size_t)s * K];
        cnt += (v & 0xFFFFu);
        pos += (v >> 16);
    }
    atomicAdd(&fineHist[bin], (u64)cnt | ((u64)pos << 32));
}

// Full exclusive descending prefix of fineHist -> prefixD[d], d=0 highest bin.
__global__ void __launch_bounds__(1024)
scan_full(const u64* __restrict__ fineHist, u64* __restrict__ prefixD)
{
    __shared__ u64 sh[1024];
    const int t = threadIdx.x;
    u64 v0 = fineHist[K - 1 - (4 * t + 0)];
    u64 v1 = fineHist[K - 1 - (4 * t + 1)];
    u64 v2 = fineHist[K - 1 - (4 * t + 2)];
    u64 v3 = fineHist[K - 1 - (4 * t + 3)];
    u64 s0 = v0, s1 = s0 + v1, s2 = s1 + v2, s3 = s2 + v3;
    sh[t] = s3;
    __syncthreads();
    for (int off = 1; off < 1024; off <<= 1) {
        u64 v = (t >= off) ? sh[t - off] : 0ULL;
        __syncthreads();
        sh[t] += v;
        __syncthreads();
    }
    u64 excl = sh[t] - s3;
    prefixD[4 * t + 0] = excl;
    prefixD[4 * t + 1] = excl + s0;
    prefixD[4 * t + 2] = excl + s1;
    prefixD[4 * t + 3] = excl + s2;
}

// AP contributions: one wave per 4 bins, lanes parallelize the j-loop.
__global__ void __launch_bounds__(256)
ap_kernel(const u64* __restrict__ fineHist, const u64* __restrict__ prefixD,
          double* __restrict__ apPartial)
{
    __shared__ double sd[4];
    const int t = threadIdx.x;
    const int lane = t & 63;
    const int wave = t >> 6;
    float acc = 0.0f;
    #pragma unroll
    for (int q = 0; q < 4; ++q) {
        int d = blockIdx.x * 16 + wave * 4 + q;
        u64 h = fineHist[K - 1 - d];
        u32 Cv = (u32)h;
        u32 Pv = (u32)(h >> 32);
        if (Pv) {
            u64 e = prefixD[d];
            float Nb = (float)(u32)e;
            float Pb = (float)(u32)(e >> 32);
            float ratio = (float)Cv / (float)Pv;
            for (u32 j = (u32)lane + 1u; j <= Pv; j += 64u) {
                float jf = (float)j;
                float rank = Nb + (jf - 0.5f) * ratio + 0.5f;
                acc += (Pb + jf) / rank;
            }
        }
    }
    double dacc = (double)acc;
    #pragma unroll
    for (int off = 32; off > 0; off >>= 1)
        dacc += __shfl_down(dacc, off);
    if (lane == 0) sd[wave] = dacc;
    __syncthreads();
    if (t == 0) apPartial[blockIdx.x] = sd[0] + sd[1] + sd[2] + sd[3];
}

__global__ void __launch_bounds__(128)
finalize(const u32* __restrict__ counters, const u64* __restrict__ prefixD,
         const double* __restrict__ apPartial,
         const float* __restrict__ loss, int N, float* __restrict__ out)
{
    __shared__ double sd[128];
    const int t = threadIdx.x;
    sd[t] = apPartial[t] + apPartial[t + 128];
    __syncthreads();
    for (int off = 64; off > 0; off >>= 1) {
        if (t < off) sd[t] += sd[t + off];
        __syncthreads();
    }

    const u32 tpS = counters[0], lblS = counters[1], predS = counters[2];
    const float nF = (float)N;

    if (t <= 100) {
        // elements / positives in regions > t (i.e. p1 > th_t), exact
        u64 pv = prefixD[K - (t + 1) * 40];
        float above  = (float)(u32)pv;
        float aboveP = (float)(u32)(pv >> 32);
        float totPos = (float)lblS;
        float idx_f = nF - above;
        float tp_t = aboveP;
        float fn_t = totPos - aboveP;
        float tn_t = idx_f - fn_t;
        float fp_t = nF - idx_f - tp_t;
        out[5 + t]   = safe_div_f(tp_t, tp_t + fp_t);  // prec_t
        out[106 + t] = safe_div_f(tp_t, tp_t + fn_t);  // rec_t
        out[207 + t] = (float)t * 0.01f;               // ths
        out[308 + t] = safe_div_f(tn_t, tn_t + fp_t);  // spec_t
    }

    if (t == 0) {
        float tp0 = (float)tpS;
        float fn0 = (float)(lblS - tpS);
        float fp0 = (float)(predS - tpS);
        float tn0 = (float)((u32)N - lblS - predS + tpS);
        double denom = (lblS > 0u) ? (double)lblS : 1.0;
        out[0] = tn0; out[1] = fp0; out[2] = fn0; out[3] = tp0;
        out[4] = (float)(sd[0] / denom);
        out[409] = safe_div_f(tp0, tp0 + fn0);
        out[410] = safe_div_f(tp0, tp0 + fp0);
        out[411] = safe_div_f(tn0, tn0 + fp0);
        out[412] = (tp0 + tn0) / nF;
        out[413] = (loss[0] + loss[1] + loss[2] + loss[3]) * 0.25f;
    }
}

extern "C" void kernel_launch(void* const* d_in, const int* in_sizes, int n_in,
                              void* d_out, int out_size, void* d_ws, size_t ws_size,
                              hipStream_t stream)
{
    const float* logits  = (const float*)d_in[0];
    const int*   targets = (const int*)d_in[1];
    const float* loss    = (const float*)d_in[2];
    const int N = in_sizes[1];

    char* ws = (char*)d_ws;
    size_t off = 0;
    u32* partials = (u32*)(ws + off);   off += (size_t)NBLK * K * 4;   // 8 MB
    u64* fineHist = (u64*)(ws + off);   off += (size_t)K * 8;          // 32 KB
    u32* counters = (u32*)(ws + off);   off += 32;
    u64* prefixD  = (u64*)(ws + off);   off += (size_t)K * 8;          // 32 KB
    double* apPartial = (double*)(ws + off);                           // 2 KB

    hipMemsetAsync(fineHist, 0, (size_t)K * 8 + 32, stream);

    main_pass<<<NBLK, TPB, 0, stream>>>(logits, targets, N, partials, counters);
    reduce_hist<<<128, 256, 0, stream>>>(partials, fineHist);
    scan_full<<<1, 1024, 0, stream>>>(fineHist, prefixD);
    ap_kernel<<<APB, 256, 0, stream>>>(fineHist, prefixD, apPartial);
    finalize<<<1, 128, 0, stream>>>(counters, prefixD, apPartial, loss, N, (float*)d_out);
}

// Round 6
// 63.840 us; speedup vs baseline: 1.0113x; 1.0113x over previous
//
#include <hip/hip_runtime.h>

typedef unsigned int u32;
typedef unsigned long long u64;

// ---------------------------------------------------------------------------
// Output layout (float32, 414 elems):
//  [0..3] confmat [tn,fp,fn,tp]; [4] map_; [5..105] prec_t; [106..206] rec_t;
//  [207..307] ths; [308..408] spec_t; [409..413] recall,precision,specificity,
//  accuracy, loss_out
//
// Fine histogram: 4096 bins = 102 threshold-aligned regions x 40 sub-bins
// (validated exact, absmax 0.0 in rounds 2-5).
//
// main_pass: global_load_lds staged pipeline. Tile = 1024 elements
// (logits 8KB = 8 chunks, targets 4KB = 4 chunks; 1 chunk = 64 lanes x 16B).
// Waves 0-7 stage logits chunks, 8-11 stage targets chunks, each exactly ONE
// global_load_lds per tile -> per-wave vmcnt counting is uniform. 4-deep ring
// buffer, prefetch distance 3; loop: s_waitcnt vmcnt(2) / s_barrier /
// prefetch(i+3) / process(i). Tail iterations re-stage the last tile into the
// dead buffer slot to keep outstanding-count invariant (dup is never read).
//
// Workspace: partials NBLK*K*4 | fineHist K*8 | counters 32B | prefixD K*8 |
//            apPartial APB*8
// ---------------------------------------------------------------------------

#define K     4096
#define NBLK  512
#define TPB   1024
#define TILE  1024
#define APB   256

static __device__ __forceinline__ float safe_div_f(float a, float b) {
    return (b > 0.0f) ? (a / fmaxf(b, 1.0f)) : 0.0f;
}

static __device__ __forceinline__ void gload16(const void* g, void* l) {
    __builtin_amdgcn_global_load_lds(
        (const __attribute__((address_space(1))) void*)g,
        (__attribute__((address_space(3))) void*)l, 16, 0, 0);
}

static __device__ __forceinline__ void proc(
    float l0, float l1, int lbl,
    u32& tp, u32& lblS, u32& predS, u32* __restrict__ fineLDS)
{
    float d = l1 - l0;
    u32 pred = (d > 0.0f) ? 1u : 0u;            // argmax: ties -> 0
    float e = __expf(-fabsf(d));                // in (0,1]
    float pl = e * __builtin_amdgcn_rcpf(1.0f + e);   // min(p1,1-p1)
    float p1 = pred ? (1.0f - pl) : pl;

    tp    += ((u32)lbl & pred);
    lblS  += (u32)lbl;
    predS += pred;

    // smallest k in [0,101] with p1 <= (float)k * 0.01f (self-consistent)
    int k = (int)ceilf(p1 * 100.0f);
    k = min(max(k, 0), 101);
    if (k > 0 && p1 <= (float)(k - 1) * 0.01f) --k;
    else if (k <= 100 && p1 > (float)k * 0.01f) ++k;

    // 40 sub-bins within region k (ordering only)
    float lo = (float)(k - 1) * 0.01f;
    int sub = (int)((p1 - lo) * 4000.0f);
    sub = min(max(sub, 0), 39);

    atomicAdd(&fineLDS[k * 40 + sub], 1u | ((u32)lbl << 16));
}

__global__ void __launch_bounds__(TPB, 8)
main_pass(const float* __restrict__ logits, const int* __restrict__ targets,
          int N, u32* __restrict__ partials, u32* __restrict__ counters)
{
    __shared__ float bufL[4][TILE * 2];   // 32 KB
    __shared__ int   bufT[4][TILE];       // 16 KB
    __shared__ u32   fineLDS[K];          // 16 KB
    __shared__ u32   sConf[3];

    const int t    = threadIdx.x;
    const int w    = t >> 6;              // wave 0..15
    const int lane = t & 63;

    for (int i = t; i < K; i += TPB) fineLDS[i] = 0u;
    if (t < 3) sConf[t] = 0u;
    asm volatile("s_waitcnt lgkmcnt(0)" ::: "memory");
    __builtin_amdgcn_s_barrier();

    const int nTiles  = N / TILE;
    const int myCount = (nTiles - blockIdx.x + NBLK - 1) / NBLK;  // >= 30
    const int i0      = blockIdx.x;       // tile(i) = i0 + i*NBLK

    // stage one tile into ring slot bi (each stager wave: exactly 1 load)
    auto stage = [&](int tileId, int bi) {
        if (w < 8) {
            const float4* src = (const float4*)logits
                              + (size_t)tileId * (TILE / 2) + (w << 6) + lane;
            gload16(src, &bufL[bi][w << 8]);
        } else if (w < 12) {
            const int wt = w - 8;
            const int4* src = (const int4*)targets
                            + (size_t)tileId * (TILE / 4) + (wt << 6) + lane;
            gload16(src, &bufT[bi][wt << 8]);
        }
    };

    u32 tp = 0u, lblS = 0u, predS = 0u;

    // prologue: 3 tiles in flight
    stage(i0,            0);
    stage(i0 + NBLK,     1);
    stage(i0 + 2 * NBLK, 2);

    for (int i = 0; i < myCount; ++i) {
        const int bi = i & 3;
        asm volatile("s_waitcnt vmcnt(2)" ::: "memory");   // tile i landed
        __builtin_amdgcn_s_barrier();                      // all waves' chunks
        // prefetch tile i+3 (dup-stage last tile at tail: never read)
        int nj = i + 3; if (nj > myCount - 1) nj = myCount - 1;
        stage(i0 + nj * NBLK, (i + 3) & 3);
        // process tile i (1 element per thread)
        float2 lg = ((float2*)bufL[bi])[t];
        int   lbl = bufT[bi][t];
        proc(lg.x, lg.y, lbl, tp, lblS, predS, fineLDS);
    }

    // remainder elements (none for N=16M; kept for generality)
    if (blockIdx.x == 0) {
        for (int x = nTiles * TILE + t; x < N; x += TPB)
            proc(logits[2 * x], logits[2 * x + 1], targets[x],
                 tp, lblS, predS, fineLDS);
    }

    #pragma unroll
    for (int off = 32; off > 0; off >>= 1) {
        tp    += __shfl_down(tp, off);
        lblS  += __shfl_down(lblS, off);
        predS += __shfl_down(predS, off);
    }
    if ((t & 63) == 0) {
        atomicAdd(&sConf[0], tp);
        atomicAdd(&sConf[1], lblS);
        atomicAdd(&sConf[2], predS);
    }
    __syncthreads();
    if (t < 3 && sConf[t]) atomicAdd(&counters[t], sConf[t]);

    // non-atomic coalesced flush
    u32* dst = partials + (size_t)blockIdx.x * K;
    for (int i2 = t; i2 < K; i2 += TPB) dst[i2] = fineLDS[i2];
}

// Fold NBLK slices into u64 fineHist. grid = 16 chunks x 8 groups = 128 blocks.
__global__ void __launch_bounds__(256)
reduce_hist(const u32* __restrict__ partials, u64* __restrict__ fineHist)
{
    const int chunk = blockIdx.x & 15;
    const int grp   = blockIdx.x >> 4;          // 0..7, 64 slices each
    const int bin = chunk * 256 + threadIdx.x;
    u32 cnt = 0u, pos = 0u;
    const u32* p = partials + (size_t)(grp * 64) * K + bin;
    #pragma unroll 8
    for (int s = 0; s < 64; ++s) {
        u32 v = p[(size_t)s * K];
        cnt += (v & 0xFFFFu);
        pos += (v >> 16);
    }
    atomicAdd(&fineHist[bin], (u64)cnt | ((u64)pos << 32));
}

// Full exclusive descending prefix of fineHist -> prefixD[d], d=0 highest bin.
__global__ void __launch_bounds__(1024)
scan_full(const u64* __restrict__ fineHist, u64* __restrict__ prefixD)
{
    __shared__ u64 sh[1024];
    const int t = threadIdx.x;
    u64 v0 = fineHist[K - 1 - (4 * t + 0)];
    u64 v1 = fineHist[K - 1 - (4 * t + 1)];
    u64 v2 = fineHist[K - 1 - (4 * t + 2)];
    u64 v3 = fineHist[K - 1 - (4 * t + 3)];
    u64 s0 = v0, s1 = s0 + v1, s2 = s1 + v2, s3 = s2 + v3;
    sh[t] = s3;
    __syncthreads();
    for (int off = 1; off < 1024; off <<= 1) {
        u64 v = (t >= off) ? sh[t - off] : 0ULL;
        __syncthreads();
        sh[t] += v;
        __syncthreads();
    }
    u64 excl = sh[t] - s3;
    prefixD[4 * t + 0] = excl;
    prefixD[4 * t + 1] = excl + s0;
    prefixD[4 * t + 2] = excl + s1;
    prefixD[4 * t + 3] = excl + s2;
}

// AP contributions: one wave per 4 bins, lanes parallelize the j-loop.
__global__ void __launch_bounds__(256)
ap_kernel(const u64* __restrict__ fineHist, const u64* __restrict__ prefixD,
          double* __restrict__ apPartial)
{
    __shared__ double sd[4];
    const int t = threadIdx.x;
    const int lane = t & 63;
    const int wave = t >> 6;
    float acc = 0.0f;
    #pragma unroll
    for (int q = 0; q < 4; ++q) {
        int d = blockIdx.x * 16 + wave * 4 + q;
        u64 h = fineHist[K - 1 - d];
        u32 Cv = (u32)h;
        u32 Pv = (u32)(h >> 32);
        if (Pv) {
            u64 e = prefixD[d];
            float Nb = (float)(u32)e;
            float Pb = (float)(u32)(e >> 32);
            float ratio = (float)Cv / (float)Pv;
            for (u32 j = (u32)lane + 1u; j <= Pv; j += 64u) {
                float jf = (float)j;
                float rank = Nb + (jf - 0.5f) * ratio + 0.5f;
                acc += (Pb + jf) / rank;
            }
        }
    }
    double dacc = (double)acc;
    #pragma unroll
    for (int off = 32; off > 0; off >>= 1)
        dacc += __shfl_down(dacc, off);
    if (lane == 0) sd[wave] = dacc;
    __syncthreads();
    if (t == 0) apPartial[blockIdx.x] = sd[0] + sd[1] + sd[2] + sd[3];
}

__global__ void __launch_bounds__(128)
finalize(const u32* __restrict__ counters, const u64* __restrict__ prefixD,
         const double* __restrict__ apPartial,
         const float* __restrict__ loss, int N, float* __restrict__ out)
{
    __shared__ double sd[128];
    const int t = threadIdx.x;
    sd[t] = apPartial[t] + apPartial[t + 128];
    __syncthreads();
    for (int off = 64; off > 0; off >>= 1) {
        if (t < off) sd[t] += sd[t + off];
        __syncthreads();
    }

    const u32 tpS = counters[0], lblS = counters[1], predS = counters[2];
    const float nF = (float)N;

    if (t <= 100) {
        u64 pv = prefixD[K - (t + 1) * 40];
        float above  = (float)(u32)pv;
        float aboveP = (float)(u32)(pv >> 32);
        float totPos = (float)lblS;
        float idx_f = nF - above;
        float tp_t = aboveP;
        float fn_t = totPos - aboveP;
        float tn_t = idx_f - fn_t;
        float fp_t = nF - idx_f - tp_t;
        out[5 + t]   = safe_div_f(tp_t, tp_t + fp_t);  // prec_t
        out[106 + t] = safe_div_f(tp_t, tp_t + fn_t);  // rec_t
        out[207 + t] = (float)t * 0.01f;               // ths
        out[308 + t] = safe_div_f(tn_t, tn_t + fp_t);  // spec_t
    }

    if (t == 0) {
        float tp0 = (float)tpS;
        float fn0 = (float)(lblS - tpS);
        float fp0 = (float)(predS - tpS);
        float tn0 = (float)((u32)N - lblS - predS + tpS);
        double denom = (lblS > 0u) ? (double)lblS : 1.0;
        out[0] = tn0; out[1] = fp0; out[2] = fn0; out[3] = tp0;
        out[4] = (float)(sd[0] / denom);
        out[409] = safe_div_f(tp0, tp0 + fn0);
        out[410] = safe_div_f(tp0, tp0 + fp0);
        out[411] = safe_div_f(tn0, tn0 + fp0);
        out[412] = (tp0 + tn0) / nF;
        out[413] = (loss[0] + loss[1] + loss[2] + loss[3]) * 0.25f;
    }
}

extern "C" void kernel_launch(void* const* d_in, const int* in_sizes, int n_in,
                              void* d_out, int out_size, void* d_ws, size_t ws_size,
                              hipStream_t stream)
{
    const float* logits  = (const float*)d_in[0];
    const int*   targets = (const int*)d_in[1];
    const float* loss    = (const float*)d_in[2];
    const int N = in_sizes[1];

    char* ws = (char*)d_ws;
    size_t off = 0;
    u32* partials = (u32*)(ws + off);   off += (size_t)NBLK * K * 4;   // 8 MB
    u64* fineHist = (u64*)(ws + off);   off += (size_t)K * 8;          // 32 KB
    u32* counters = (u32*)(ws + off);   off += 32;
    u64* prefixD  = (u64*)(ws + off);   off += (size_t)K * 8;          // 32 KB
    double* apPartial = (double*)(ws + off);                           // 2 KB

    hipMemsetAsync(fineHist, 0, (size_t)K * 8 + 32, stream);

    main_pass<<<NBLK, TPB, 0, stream>>>(logits, targets, N, partials, counters);
    reduce_hist<<<128, 256, 0, stream>>>(partials, fineHist);
    scan_full<<<1, 1024, 0, stream>>>(fineHist, prefixD);
    ap_kernel<<<APB, 256, 0, stream>>>(fineHist, prefixD, apPartial);
    finalize<<<1, 128, 0, stream>>>(counters, prefixD, apPartial, loss, N, (float*)d_out);
}